// Round 1
// baseline (221.978 us; speedup 1.0000x reference)
//
#include <hip/hip_runtime.h>
#include <hip/hip_bf16.h>

#define ETA_MIN 0.6931471805599453f
#define ETA_MAX 10.0f

// Streaming elementwise: w_i = (loss_i > eta) ? 0 : 1 - loss_i/eta
// eta = clamp(eta_value[0], log(2), 10). Memory-bound: 256 MB traffic.
__global__ void __launch_bounds__(256) weights_kernel(
    const float* __restrict__ loss,
    const float* __restrict__ eta_value,
    float* __restrict__ out,
    int n4,          // number of float4 elements
    int tail_start,  // n4*4
    int n)           // total elements
{
    // Uniform load — compiler proves uniformity, emits scalar load; L2-cached.
    float eta = eta_value[0];
    eta = fminf(fmaxf(eta, ETA_MIN), ETA_MAX);
    const float inv = 1.0f / eta;

    const int i = blockIdx.x * blockDim.x + threadIdx.x;

    if (i < n4) {
        const float4 l = reinterpret_cast<const float4*>(loss)[i];
        float4 w;
        w.x = (l.x > eta) ? 0.0f : fmaf(-l.x, inv, 1.0f);
        w.y = (l.y > eta) ? 0.0f : fmaf(-l.y, inv, 1.0f);
        w.z = (l.z > eta) ? 0.0f : fmaf(-l.z, inv, 1.0f);
        w.w = (l.w > eta) ? 0.0f : fmaf(-l.w, inv, 1.0f);
        reinterpret_cast<float4*>(out)[i] = w;
    }

    // Scalar tail (n not divisible by 4). For N=2^25 this branch is dead.
    const int t = tail_start + i;
    if (i < n - tail_start) {
        const float l = loss[t];
        out[t] = (l > eta) ? 0.0f : fmaf(-l, inv, 1.0f);
    }
}

extern "C" void kernel_launch(void* const* d_in, const int* in_sizes, int n_in,
                              void* d_out, int out_size, void* d_ws, size_t ws_size,
                              hipStream_t stream) {
    const float* loss = (const float*)d_in[0];
    const float* eta  = (const float*)d_in[1];
    float* out        = (float*)d_out;
    const int n  = in_sizes[0];
    const int n4 = n / 4;
    const int tail_start = n4 * 4;

    const int block = 256;
    int work = n4 > (n - tail_start) ? n4 : (n - tail_start);
    if (work < 1) work = 1;
    const int grid = (work + block - 1) / block;

    weights_kernel<<<grid, block, 0, stream>>>(loss, eta, out, n4, tail_start, n);
}

// Round 3
// 219.700 us; speedup vs baseline: 1.0104x; 1.0104x over previous
//
#include <hip/hip_runtime.h>
#include <hip/hip_bf16.h>

#define ETA_MIN 0.6931471805599453f
#define ETA_MAX 10.0f

// Native vector type — __builtin_nontemporal_* rejects HIP_vector_type structs
// but accepts ext_vector_type. Lowers to global_{load,store}_dwordx4 nt.
typedef float vfloat4 __attribute__((ext_vector_type(4)));

// Streaming elementwise: w_i = (loss_i > eta) ? 0 : 1 - loss_i/eta
// eta = clamp(eta_value[0], log(2), 10).
// 256 MB total traffic (>> 32 MB L2) with zero reuse -> non-temporal
// loads/stores to bypass L2 allocation on both streams.
__global__ void __launch_bounds__(256) weights_kernel(
    const float* __restrict__ loss,
    const float* __restrict__ eta_value,
    float* __restrict__ out,
    int n4,          // number of float4 elements
    int tail_start,  // n4*4
    int n)           // total elements
{
    // Uniform load — scalar path, L2-cached, negligible.
    float eta = eta_value[0];
    eta = fminf(fmaxf(eta, ETA_MIN), ETA_MAX);
    const float inv = 1.0f / eta;

    const int i = blockIdx.x * blockDim.x + threadIdx.x;

    if (i < n4) {
        const vfloat4 l =
            __builtin_nontemporal_load(reinterpret_cast<const vfloat4*>(loss) + i);
        vfloat4 w;
        w.x = (l.x > eta) ? 0.0f : fmaf(-l.x, inv, 1.0f);
        w.y = (l.y > eta) ? 0.0f : fmaf(-l.y, inv, 1.0f);
        w.z = (l.z > eta) ? 0.0f : fmaf(-l.z, inv, 1.0f);
        w.w = (l.w > eta) ? 0.0f : fmaf(-l.w, inv, 1.0f);
        __builtin_nontemporal_store(w, reinterpret_cast<vfloat4*>(out) + i);
    }

    // Scalar tail (n not divisible by 4). Dead for N=2^25.
    const int t = tail_start + i;
    if (i < n - tail_start) {
        const float l = loss[t];
        out[t] = (l > eta) ? 0.0f : fmaf(-l, inv, 1.0f);
    }
}

extern "C" void kernel_launch(void* const* d_in, const int* in_sizes, int n_in,
                              void* d_out, int out_size, void* d_ws, size_t ws_size,
                              hipStream_t stream) {
    const float* loss = (const float*)d_in[0];
    const float* eta  = (const float*)d_in[1];
    float* out        = (float*)d_out;
    const int n  = in_sizes[0];
    const int n4 = n / 4;
    const int tail_start = n4 * 4;

    const int block = 256;
    int work = n4 > (n - tail_start) ? n4 : (n - tail_start);
    if (work < 1) work = 1;
    const int grid = (work + block - 1) / block;

    weights_kernel<<<grid, block, 0, stream>>>(loss, eta, out, n4, tail_start, n);
}